// Round 2
// baseline (241.394 us; speedup 1.0000x reference)
//
#include <hip/hip_runtime.h>

#define NROW 513
#define NCOL 65
#define DD   64
#define NN   512
#define NLAYER 4
#define TPB  512
#define NWAVE 8

typedef float f32x16 __attribute__((ext_vector_type(16)));
typedef short s16x8  __attribute__((ext_vector_type(8)));

__device__ __forceinline__ short bf16_rne(float f) {
    unsigned u = __builtin_bit_cast(unsigned, f);
    u += 0x7FFFu + ((u >> 16) & 1u);
    return (short)(u >> 16);
}

// Math (per batch b): X = Z[:,:64] invariant, y = Z[:,64].
//   G = X[:512]^T X[:512]  (64x64, bf16 MFMA, f32 accum)
//   s1 = X[:512]^T y0[:512]
//   l=1..4: s = s1 + G u; rho = gamma_l*rho + (q_l/512)*s; u += alpha_l*rho
//   out = Z with col64 = y0 + X u
__launch_bounds__(TPB, 4)
__global__ void tf_kernel(const float* __restrict__ Zin,
                          const float* __restrict__ allparam,
                          const float* __restrict__ gam,
                          const float* __restrict__ alp,
                          float* __restrict__ out) {
    __shared__ float yl[NN];            // y0 rows 0..511
    __shared__ float Gl[DD][DD + 1];    // padded (odd stride -> conflict-free row reads)
    __shared__ float s1l[DD];
    __shared__ float ul[DD];
    __shared__ float xul[NROW];         // X·u per row
    __shared__ float qsl[NLAYER];

    const int tid  = threadIdx.x;
    const int w    = tid >> 6;
    const int lane = tid & 63;
    const int half = lane >> 5;
    const int lc   = lane & 31;
    const long base = (long)blockIdx.x * (NROW * NCOL);

    // ---- init ----
    for (int i = tid; i < DD * (DD + 1); i += TPB) ((float*)Gl)[i] = 0.0f;
    if (tid < DD) { s1l[tid] = 0.0f; ul[tid] = 0.0f; }
    if (tid < NN) yl[tid] = Zin[base + (long)tid * NCOL + DD];
    if (tid < 64) {  // q_l = mean(diag(allparam[l,0,1]))
        for (int l = 0; l < NLAYER; ++l) {
            float v = allparam[l * 8192 + 4096 + tid * 65];
            #pragma unroll
            for (int off = 32; off > 0; off >>= 1) v += __shfl_down(v, off, 64);
            if (tid == 0) qsl[l] = v * (1.0f / 64.0f);
        }
    }
    __syncthreads();

    // ---- pass 1: G (MFMA) and s1 ----
    {
        f32x16 acc00, acc01, acc10, acc11;
        #pragma unroll
        for (int r = 0; r < 16; ++r) { acc00[r] = 0.f; acc01[r] = 0.f; acc10[r] = 0.f; acc11[r] = 0.f; }
        float sp0 = 0.f, sp1 = 0.f;

        #pragma unroll
        for (int sl = 0; sl < 4; ++sl) {          // 4 K-slices of 16 rows per wave
            const int rbase = w * 64 + sl * 16 + half * 8;
            s16x8 f0, f1;
            const float* rp = Zin + base + (long)rbase * NCOL + lc;
            #pragma unroll
            for (int e = 0; e < 8; ++e) {
                float a0 = rp[0];                  // col lc       (rows rbase+e)
                float a1 = rp[32];                 // col 32+lc
                float yv = yl[rbase + e];
                sp0 += yv * a0;
                sp1 += yv * a1;
                f0[e] = bf16_rne(a0);
                f1[e] = bf16_rne(a1);
                rp += NCOL;
            }
            acc00 = __builtin_amdgcn_mfma_f32_32x32x16_bf16(f0, f0, acc00, 0, 0, 0);
            acc01 = __builtin_amdgcn_mfma_f32_32x32x16_bf16(f0, f1, acc01, 0, 0, 0);
            acc10 = __builtin_amdgcn_mfma_f32_32x32x16_bf16(f1, f0, acc10, 0, 0, 0);
            acc11 = __builtin_amdgcn_mfma_f32_32x32x16_bf16(f1, f1, acc11, 0, 0, 0);
        }

        // s1: fold the two k-halves, then cross-wave reduce in LDS
        sp0 += __shfl_xor(sp0, 32, 64);
        sp1 += __shfl_xor(sp1, 32, 64);
        if (half == 0) {
            atomicAdd(&s1l[lc], sp0);
            atomicAdd(&s1l[32 + lc], sp1);
        }
        // G: C/D layout col=lane&31, row=(r&3)+8*(r>>2)+4*(lane>>5)  [m74/m101]
        #pragma unroll
        for (int r = 0; r < 16; ++r) {
            const int row = (r & 3) + 8 * (r >> 2) + 4 * half;
            atomicAdd(&Gl[row][lc],           acc00[r]);
            atomicAdd(&Gl[row][32 + lc],      acc01[r]);
            atomicAdd(&Gl[32 + row][lc],      acc10[r]);
            atomicAdd(&Gl[32 + row][32 + lc], acc11[r]);
        }
    }
    __syncthreads();

    // ---- 64-dim recurrence (wave 0 only) ----
    if (tid < 64) {
        const int j = tid;
        const float s1j = s1l[j];
        float u = 0.f, rho = 0.f;
        for (int l = 0; l < NLAYER; ++l) {
            float dot = 0.f;
            #pragma unroll 8
            for (int k = 0; k < DD; ++k) dot += Gl[j][k] * ul[k];
            const float s = s1j + dot;
            rho = gam[l] * rho + (qsl[l] * (1.0f / (float)NN)) * s;
            u += alp[l] * rho;
            ul[j] = u;   // wave-lockstep: write then next-layer reads are lgkm-ordered
        }
    }
    __syncthreads();

    // ---- pass 2a: xu[n] = X[n]·u  (wave per row group, coalesced row reads) ----
    {
        const float ucol = ul[lane];
        for (int n = w; n < NROW; n += NWAVE) {
            float p = Zin[base + (long)n * NCOL + lane] * ucol;
            #pragma unroll
            for (int off = 32; off > 0; off >>= 1) p += __shfl_xor(p, off, 64);
            if (lane == 0) xul[n] = p;
        }
    }
    __syncthreads();

    // ---- pass 2b: float4 flat copy with col-64 patch ----
    {
        const long gbeg = base;
        const long gend = base + (long)NROW * NCOL;
        const long abeg = (gbeg + 3) & ~3L;
        const long aend = gend & ~3L;
        // scalar head/tail (<=3 each)
        const int hcnt = (int)(abeg - gbeg);
        if (tid < hcnt) {
            const long g = gbeg + tid;
            const int li = (int)(g - base);
            float v = Zin[g];
            if (li % NCOL == DD) v += xul[li / NCOL];
            out[g] = v;
        }
        const int tcnt = (int)(gend - aend);
        if (tid >= 64 && tid < 64 + tcnt) {
            const long g = aend + (tid - 64);
            const int li = (int)(g - base);
            float v = Zin[g];
            if (li % NCOL == DD) v += xul[li / NCOL];
            out[g] = v;
        }
        for (long a = abeg + (long)tid * 4; a < aend; a += (long)TPB * 4) {
            float4 v = *(const float4*)(Zin + a);
            const int li = (int)(a - base);
            const int j = li % NCOL;
            if (j >= NCOL - 4) {          // col 64 is one of the 4 components
                if (j == DD)          v.x += xul[li / NCOL];
                else if (j == DD - 1) v.y += xul[(li + 1) / NCOL];
                else if (j == DD - 2) v.z += xul[(li + 2) / NCOL];
                else                  v.w += xul[(li + 3) / NCOL];
            }
            *(float4*)(out + a) = v;
        }
    }
}

extern "C" void kernel_launch(void* const* d_in, const int* in_sizes, int n_in,
                              void* d_out, int out_size, void* d_ws, size_t ws_size,
                              hipStream_t stream) {
    const float* Z        = (const float*)d_in[0];
    const float* allparam = (const float*)d_in[1];
    const float* gam      = (const float*)d_in[2];
    const float* alp      = (const float*)d_in[3];
    float* outp = (float*)d_out;
    tf_kernel<<<dim3(512), dim3(TPB), 0, stream>>>(Z, allparam, gam, alp, outp);
}

// Round 3
// 225.269 us; speedup vs baseline: 1.0716x; 1.0716x over previous
//
#include <hip/hip_runtime.h>

#define NROW 513
#define NCOL 65
#define DD   64
#define NN   512
#define NLAYER 4
#define TPB  512
#define NWAVE 8

typedef float f32x16 __attribute__((ext_vector_type(16)));
typedef short s16x8  __attribute__((ext_vector_type(8)));

__device__ __forceinline__ short bf16_rne(float f) {
    unsigned u = __builtin_bit_cast(unsigned, f);
    u += 0x7FFFu + ((u >> 16) & 1u);
    return (short)(u >> 16);
}

// Math (per batch b): X = Z[:,:64] invariant, y = Z[:,64].
//   G = X[:512]^T X[:512]  (64x64, bf16 MFMA, f32 accum)
//   s1 = X[:512]^T y0[:512]
//   l=1..4: s = s1 + G u; rho = gamma_l*rho + (q_l/512)*s; u += alpha_l*rho
//   out = Z with col64 = y0 + X u
// NOTE: no min-waves in __launch_bounds__ — R2's (512,4) capped VGPR=64 and
// spilled the 64-VGPR accumulator set to scratch (155us disaster).
__global__ __launch_bounds__(TPB)
void tf_kernel(const float* __restrict__ Zin,
               const float* __restrict__ allparam,
               const float* __restrict__ gam,
               const float* __restrict__ alp,
               float* __restrict__ out) {
    __shared__ float yl[NN];            // y0 rows 0..511
    __shared__ float Gl[DD][DD + 1];    // padded (odd stride -> conflict-free)
    __shared__ float s1l[DD];
    __shared__ float ul[DD];
    __shared__ float xul[NROW];         // X·u per row
    __shared__ float qsl[NLAYER];

    const int tid  = threadIdx.x;
    const int w    = tid >> 6;
    const int lane = tid & 63;
    const int half = lane >> 5;
    const int lc   = lane & 31;
    const long base = (long)blockIdx.x * (NROW * NCOL);

    // ---- init ----
    for (int i = tid; i < DD * (DD + 1); i += TPB) ((float*)Gl)[i] = 0.0f;
    if (tid < DD) { s1l[tid] = 0.0f; ul[tid] = 0.0f; }
    if (tid < NN) yl[tid] = Zin[base + (long)tid * NCOL + DD];
    if (tid < 64) {  // q_l = mean(diag(allparam[l,0,1]))
        for (int l = 0; l < NLAYER; ++l) {
            float v = allparam[l * 8192 + 4096 + tid * 65];
            #pragma unroll
            for (int off = 32; off > 0; off >>= 1) v += __shfl_down(v, off, 64);
            if (tid == 0) qsl[l] = v * (1.0f / 64.0f);
        }
    }
    __syncthreads();

    // ---- pass 1: G (MFMA) and s1 ----
    {
        f32x16 acc00, acc01, acc10, acc11;
        #pragma unroll
        for (int r = 0; r < 16; ++r) { acc00[r] = 0.f; acc01[r] = 0.f; acc10[r] = 0.f; acc11[r] = 0.f; }
        float sp0 = 0.f, sp1 = 0.f;

        #pragma unroll
        for (int sl = 0; sl < 4; ++sl) {          // 4 K-slices of 16 rows per wave
            const int rbase = w * 64 + sl * 16 + half * 8;
            s16x8 f0, f1;
            const float* rp = Zin + base + (long)rbase * NCOL + lc;
            #pragma unroll
            for (int e = 0; e < 8; ++e) {
                float a0 = rp[0];                  // col lc       (row rbase+e)
                float a1 = rp[32];                 // col 32+lc
                float yv = yl[rbase + e];
                sp0 += yv * a0;
                sp1 += yv * a1;
                f0[e] = bf16_rne(a0);
                f1[e] = bf16_rne(a1);
                rp += NCOL;
            }
            acc00 = __builtin_amdgcn_mfma_f32_32x32x16_bf16(f0, f0, acc00, 0, 0, 0);
            acc01 = __builtin_amdgcn_mfma_f32_32x32x16_bf16(f0, f1, acc01, 0, 0, 0);
            acc10 = __builtin_amdgcn_mfma_f32_32x32x16_bf16(f1, f0, acc10, 0, 0, 0);
            acc11 = __builtin_amdgcn_mfma_f32_32x32x16_bf16(f1, f1, acc11, 0, 0, 0);
        }

        sp0 += __shfl_xor(sp0, 32, 64);
        sp1 += __shfl_xor(sp1, 32, 64);
        if (half == 0) {
            atomicAdd(&s1l[lc], sp0);
            atomicAdd(&s1l[32 + lc], sp1);
        }
        // C/D layout: col=lane&31, row=(r&3)+8*(r>>2)+4*(lane>>5)  [m74/m101]
        #pragma unroll
        for (int r = 0; r < 16; ++r) {
            const int row = (r & 3) + 8 * (r >> 2) + 4 * half;
            atomicAdd(&Gl[row][lc],           acc00[r]);
            atomicAdd(&Gl[row][32 + lc],      acc01[r]);
            atomicAdd(&Gl[32 + row][lc],      acc10[r]);
            atomicAdd(&Gl[32 + row][32 + lc], acc11[r]);
        }
    }
    __syncthreads();

    // ---- 64-dim recurrence (wave 0 only) ----
    if (tid < 64) {
        const int j = tid;
        const float s1j = s1l[j];
        float u = 0.f, rho = 0.f;
        for (int l = 0; l < NLAYER; ++l) {
            float dot = 0.f;
            #pragma unroll 8
            for (int k = 0; k < DD; ++k) dot += Gl[j][k] * ul[k];
            const float s = s1j + dot;
            rho = gam[l] * rho + (qsl[l] * (1.0f / (float)NN)) * s;
            u += alp[l] * rho;
            ul[j] = u;   // wave-lockstep; in-order LDS per wave
        }
    }
    __syncthreads();

    // ---- pass 2a: xu[n] = X[n]·u  (4 rows in flight -> shuffle chains overlap) ----
    {
        const float ucol = ul[lane];
        int n = w;
        for (; n + 24 < NROW; n += 4 * NWAVE) {
            float p0 = Zin[base + (long)(n             ) * NCOL + lane] * ucol;
            float p1 = Zin[base + (long)(n +     NWAVE) * NCOL + lane] * ucol;
            float p2 = Zin[base + (long)(n + 2 * NWAVE) * NCOL + lane] * ucol;
            float p3 = Zin[base + (long)(n + 3 * NWAVE) * NCOL + lane] * ucol;
            #pragma unroll
            for (int off = 32; off > 0; off >>= 1) {
                p0 += __shfl_xor(p0, off, 64);
                p1 += __shfl_xor(p1, off, 64);
                p2 += __shfl_xor(p2, off, 64);
                p3 += __shfl_xor(p3, off, 64);
            }
            if (lane == 0) {
                xul[n] = p0; xul[n + NWAVE] = p1;
                xul[n + 2 * NWAVE] = p2; xul[n + 3 * NWAVE] = p3;
            }
        }
        for (; n < NROW; n += NWAVE) {
            float p = Zin[base + (long)n * NCOL + lane] * ucol;
            #pragma unroll
            for (int off = 32; off > 0; off >>= 1) p += __shfl_xor(p, off, 64);
            if (lane == 0) xul[n] = p;
        }
    }
    __syncthreads();

    // ---- pass 2b: float4 flat copy with inline col-64 patch (full-line writes) ----
    {
        const long gbeg = base;
        const long gend = base + (long)NROW * NCOL;
        const long abeg = (gbeg + 3) & ~3L;
        const long aend = gend & ~3L;
        const int hcnt = (int)(abeg - gbeg);
        if (tid < hcnt) {
            const long g = gbeg + tid;
            const int li = (int)(g - base);
            float v = Zin[g];
            if (li % NCOL == DD) v += xul[li / NCOL];
            out[g] = v;
        }
        const int tcnt = (int)(gend - aend);
        if (tid >= 64 && tid < 64 + tcnt) {
            const long g = aend + (tid - 64);
            const int li = (int)(g - base);
            float v = Zin[g];
            if (li % NCOL == DD) v += xul[li / NCOL];
            out[g] = v;
        }
        for (long a = abeg + (long)tid * 4; a < aend; a += (long)TPB * 4) {
            float4 v = *(const float4*)(Zin + a);
            const int li = (int)(a - base);
            const int j = li % NCOL;
            if (j >= NCOL - 4) {
                if (j == DD)          v.x += xul[li / NCOL];
                else if (j == DD - 1) v.y += xul[(li + 1) / NCOL];
                else if (j == DD - 2) v.z += xul[(li + 2) / NCOL];
                else                  v.w += xul[(li + 3) / NCOL];
            }
            *(float4*)(out + a) = v;
        }
    }
}

extern "C" void kernel_launch(void* const* d_in, const int* in_sizes, int n_in,
                              void* d_out, int out_size, void* d_ws, size_t ws_size,
                              hipStream_t stream) {
    const float* Z        = (const float*)d_in[0];
    const float* allparam = (const float*)d_in[1];
    const float* gam      = (const float*)d_in[2];
    const float* alp      = (const float*)d_in[3];
    float* outp = (float*)d_out;
    tf_kernel<<<dim3(512), dim3(TPB), 0, stream>>>(Z, allparam, gam, alp, outp);
}

// Round 6
// 176.660 us; speedup vs baseline: 1.3664x; 1.2752x over previous
//
#include <hip/hip_runtime.h>

#define NROW 513
#define NCOL 65
#define DD   64
#define NN   512
#define NLAYER 4
#define TPB  1024
#define TOT  (NROW * NCOL)   // 33345

typedef float f32x16 __attribute__((ext_vector_type(16)));
typedef short s16x8  __attribute__((ext_vector_type(8)));

__device__ __forceinline__ short bf16_rne(float f) {
    unsigned u = __builtin_bit_cast(unsigned, f);
    u += 0x7FFFu + ((u >> 16) & 1u);
    return (short)(u >> 16);
}

// Per batch b: X = Z[:,:64] invariant, y = Z[:,64].
//   G = X[:512]^T X[:512] (bf16 MFMA), s1 = X[:512]^T y0[:512]
//   l: s = s1 + G u; rho = gamma_l rho + (q_l/512) s; u += alpha_l rho
//   out = Z with col64 = y0 + X u
// Structure: R1's proven single-LDS-tile design (62us) + float4 staging +
// G-math + full-line register stores. 1 block/CU (151 KB LDS), 16 waves.
__global__ __launch_bounds__(TPB)
void tf_kernel(const float* __restrict__ Zin,
               const float* __restrict__ allparam,
               const float* __restrict__ gam,
               const float* __restrict__ alp,
               float* __restrict__ out) {
    __shared__ float Zs[TOT + 3];       // flat tile, +shift alignment pad
    __shared__ float Gl[DD][DD + 1];
    __shared__ float sred[4][DD];
    __shared__ float ul[DD];
    __shared__ float qsl[NLAYER];

    const int tid  = threadIdx.x;
    const int w    = tid >> 6;
    const int lane = tid & 63;
    const int half = lane >> 5;
    const int lc   = lane & 31;
    const long base = (long)blockIdx.x * TOT;
    const int  shift = (int)(base & 3);          // LDS offset so vectors align
    const int  c     = (4 - shift) & 3;          // head scalars
    const long gbeg  = base, gend = base + TOT;
    const long abeg  = gbeg + c;
    const int  tc    = (int)(gend & 3);          // tail scalars
    const long aend  = gend - tc;
    const int  nvec  = (int)((aend - abeg) >> 2);

    // ---- init (pre-barrier) ----
    for (int i = tid; i < DD * (DD + 1); i += TPB) ((float*)Gl)[i] = 0.0f;
    if (tid < DD) ul[tid] = 0.0f;
    if (tid < 64) {  // q_l = mean(diag(allparam[l,0,1]))
        for (int l = 0; l < NLAYER; ++l) {
            float vq = allparam[l * 8192 + 4096 + tid * 65];
            #pragma unroll
            for (int off = 32; off > 0; off >>= 1) vq += __shfl_down(vq, off, 64);
            if (tid == 0) qsl[l] = vq * (1.0f / 64.0f);
        }
    }

    // ---- P1: float4 load -> registers + LDS; head written to out now ----
    float4 v[9];
    #pragma unroll
    for (int k = 0; k < 9; ++k) {
        const int u = tid + k * TPB;
        if (u < nvec) {
            const long a = abeg + (long)u * 4;
            v[k] = *(const float4*)(Zin + a);
            const int li = (int)(a - base);
            *(float4*)(&Zs[shift + li]) = v[k];   // (shift+li)%4 == 0
        }
    }
    if (tid < c) {                       // head: row 0 cols 0..2, never col 64
        const long g = gbeg + tid;
        const float x = Zin[g];
        Zs[shift + tid] = x;
        out[g] = x;
    }
    if (tc && tid >= 64 && tid < 64 + tc) {       // tail: staged, written in P5
        const long g = aend + (tid - 64);
        Zs[shift + (int)(g - base)] = Zin[g];
    }
    __syncthreads();

    // ---- P2: waves 0-3 G-MFMA (K=128 each); waves 4-7 s1 partials ----
    if (w < 4) {
        f32x16 a00, a01, a10, a11;
        #pragma unroll
        for (int r = 0; r < 16; ++r) { a00[r] = 0.f; a01[r] = 0.f; a10[r] = 0.f; a11[r] = 0.f; }
        for (int s = 0; s < 8; ++s) {
            const int rbase = w * 128 + s * 16 + half * 8;
            s16x8 f0, f1;
            const int ab = shift + rbase * NCOL + lc;
            #pragma unroll
            for (int e = 0; e < 8; ++e) {
                f0[e] = bf16_rne(Zs[ab + e * NCOL]);        // col lc
                f1[e] = bf16_rne(Zs[ab + e * NCOL + 32]);   // col 32+lc
            }
            a00 = __builtin_amdgcn_mfma_f32_32x32x16_bf16(f0, f0, a00, 0, 0, 0);
            a01 = __builtin_amdgcn_mfma_f32_32x32x16_bf16(f0, f1, a01, 0, 0, 0);
            a10 = __builtin_amdgcn_mfma_f32_32x32x16_bf16(f1, f0, a10, 0, 0, 0);
            a11 = __builtin_amdgcn_mfma_f32_32x32x16_bf16(f1, f1, a11, 0, 0, 0);
        }
        // C/D layout: col=lane&31, row=(r&3)+8*(r>>2)+4*(lane>>5)  [m74/m101]
        #pragma unroll
        for (int r = 0; r < 16; ++r) {
            const int row = (r & 3) + 8 * (r >> 2) + 4 * half;
            atomicAdd(&Gl[row][lc],           a00[r]);
            atomicAdd(&Gl[row][32 + lc],      a01[r]);
            atomicAdd(&Gl[32 + row][lc],      a10[r]);
            atomicAdd(&Gl[32 + row][32 + lc], a11[r]);
        }
    } else if (w < 8) {
        const int wg = w - 4;
        const int m0 = wg * 128;
        float acc = 0.f;
        #pragma unroll 4
        for (int m = m0; m < m0 + 128; ++m)
            acc += Zs[shift + m * NCOL + DD] * Zs[shift + m * NCOL + lane];
        sred[wg][lane] = acc;
    }
    __syncthreads();

    // ---- P3: 64-dim recurrence (wave 0) ----
    if (tid < 64) {
        const int j = tid;
        const float s1j = sred[0][j] + sred[1][j] + sred[2][j] + sred[3][j];
        float u = 0.f, rho = 0.f;
        for (int l = 0; l < NLAYER; ++l) {
            float dot = 0.f;
            #pragma unroll 8
            for (int k2 = 0; k2 < DD; ++k2) dot += Gl[j][k2] * ul[k2];
            const float s = s1j + dot;
            rho = gam[l] * rho + (qsl[l] * (1.0f / (float)NN)) * s;
            u += alp[l] * rho;
            ul[j] = u;   // wave-lockstep, in-order LDS per wave
        }
    }
    __syncthreads();

    // ---- P4: patch col 64 in LDS: Zs[n][64] += X[n]·u ----
    if (tid < NROW) {
        const int rb = shift + tid * NCOL;
        float dot = 0.f;
        #pragma unroll 8
        for (int j = 0; j < DD; ++j) dot += Zs[rb + j] * ul[j];
        Zs[rb + DD] += dot;
    }
    __syncthreads();

    // ---- P5: full-line float4 stores from registers, col-64 from LDS ----
    #pragma unroll
    for (int k = 0; k < 9; ++k) {
        const int u = tid + k * TPB;
        if (u < nvec) {
            const long a = abeg + (long)u * 4;
            const int li = (int)(a - base);
            const int j = li % NCOL;             // col of component 0
            float4 vv = v[k];
            if (j >= NCOL - 4) {                 // this float4 contains col 64
                const int comp = DD - j;         // 0..3
                const float pv = Zs[shift + li + comp];
                if      (comp == 0) vv.x = pv;
                else if (comp == 1) vv.y = pv;
                else if (comp == 2) vv.z = pv;
                else                vv.w = pv;
            }
            *(float4*)(out + a) = vv;
        }
    }
    if (tc && tid < tc) {                        // tail (may include col 64)
        const long g = aend + tid;
        out[g] = Zs[shift + (int)(g - base)];
    }
}

extern "C" void kernel_launch(void* const* d_in, const int* in_sizes, int n_in,
                              void* d_out, int out_size, void* d_ws, size_t ws_size,
                              hipStream_t stream) {
    const float* Z        = (const float*)d_in[0];
    const float* allparam = (const float*)d_in[1];
    const float* gam      = (const float*)d_in[2];
    const float* alp      = (const float*)d_in[3];
    float* outp = (float*)d_out;
    tf_kernel<<<dim3(512), dim3(TPB), 0, stream>>>(Z, allparam, gam, alp, outp);
}